// Round 20
// baseline (191.715 us; speedup 1.0000x reference)
//
#include <hip/hip_runtime.h>

#define NN 50000
#define NE 800000
#define NBC 49            // coarse buckets of 1024 dst nodes
#define MSB 391           // msplit/hist blocks (x2048 edges)

typedef __attribute__((ext_vector_type(8))) short short8;
typedef __attribute__((ext_vector_type(4))) float f32x4;

// global -> LDS direct DMA, 16B/lane, offset ALWAYS 0 (non-zero offset
// immediate is broken for this builtin — proven by round-13/14 bisection)
#define GLDS(g, l)                                                              \
  __builtin_amdgcn_global_load_lds(                                             \
      (const __attribute__((address_space(1))) void*)(g),                       \
      (__attribute__((address_space(3))) void*)(l), 16, 0, 0)

// ---------------- bf16 helpers (RNE) ----------------
__device__ __forceinline__ unsigned short f2bf(float f) {
  union { float f; unsigned u; } v; v.f = f;
  unsigned r = (v.u + 0x7FFFu + ((v.u >> 16) & 1u)) >> 16;
  return (unsigned short)r;
}
__device__ __forceinline__ float bflo(unsigned u) {
  union { unsigned x; float f; } v; v.x = u << 16; return v.f;
}
__device__ __forceinline__ float bfhi(unsigned u) {
  union { unsigned x; float f; } v; v.x = u & 0xFFFF0000u; return v.f;
}

// ---------------- threefry2x32, JAX partitionable, key = (0, 42) ----------------
__device__ __forceinline__ unsigned tf_rotl(unsigned x, int r) {
#if __has_builtin(__builtin_amdgcn_alignbit)
  return __builtin_amdgcn_alignbit(x, x, 32 - r);
#else
  return (x << r) | (x >> (32 - r));
#endif
}
__device__ __forceinline__ void threefry_0_42(unsigned x0, unsigned x1,
                                              unsigned& o0, unsigned& o1) {
  const unsigned k0 = 0u, k1 = 42u;
  const unsigned k2 = k0 ^ k1 ^ 0x1BD11BDAu;
  x0 += k0; x1 += k1;
#define TF_R(r) { x0 += x1; x1 = tf_rotl(x1, (r)); x1 ^= x0; }
  TF_R(13) TF_R(15) TF_R(26) TF_R(6)
  x0 += k1; x1 += k2 + 1u;
  TF_R(17) TF_R(29) TF_R(16) TF_R(24)
  x0 += k2; x1 += k0 + 2u;
  TF_R(13) TF_R(15) TF_R(26) TF_R(6)
  x0 += k0; x1 += k1 + 3u;
  TF_R(17) TF_R(29) TF_R(16) TF_R(24)
  x0 += k1; x1 += k2 + 4u;
  TF_R(13) TF_R(15) TF_R(26) TF_R(6)
  x0 += k2; x1 += k0 + 5u;
#undef TF_R
  o0 = x0; o1 = x1;
}
// keep iff uniform<0.9f; 0.9f == 7549747/2^23 exactly -> integer compare
__device__ __forceinline__ float dropout_scale(unsigned flat) {
  unsigned o0, o1;
  threefry_0_42(0u, flat, o0, o1);
  unsigned bits = o0 ^ o1;
  return ((bits >> 9) < 7549747u) ? (1.0f / 0.9f) : 0.0f;
}

// ---------------- fused prep: x->bf16 + weight packing + hist zero ----------------
#define CVTB 6250  // 1.6M float4 / 256
__global__ void prep_k(const float4* __restrict__ x, uint2* __restrict__ xb,
                       const float* __restrict__ Wl1, const float* __restrict__ Wr1,
                       const float* __restrict__ Wl2, const float* __restrict__ Wr2,
                       unsigned short* __restrict__ W1t, unsigned short* __restrict__ W2t,
                       unsigned* __restrict__ hist) {
  int bid = blockIdx.x;
  if (bid < CVTB) {
    int i = bid * 256 + threadIdx.x;
    float4 v = x[i];
    uint2 o;
    o.x = (unsigned)f2bf(v.x) | ((unsigned)f2bf(v.y) << 16);
    o.y = (unsigned)f2bf(v.z) | ((unsigned)f2bf(v.w) << 16);
    xb[i] = o;
  } else if (bid < CVTB + 512) {
    int gid = (bid - CVTB) * 256 + threadIdx.x;  // 131072
    int idx = gid & 65535;
    int n = idx >> 8, k = idx & 255;
    if (gid < 65536) {
      float v = (k < 128) ? Wr1[(size_t)k * 256 + n] : Wl1[(size_t)(k - 128) * 256 + n];
      W1t[idx] = f2bf(v);
    } else {
      float v = (n < 128) ? Wl2[(size_t)k * 128 + n] : Wr2[(size_t)k * 128 + (n - 128)];
      W2t[idx] = f2bf(v);
    }
  } else {
    if (threadIdx.x < 64) hist[threadIdx.x] = 0;
  }
}

// ---------------- CSR build: multi-split counting sort (r14-proven) ----------------
__global__ __launch_bounds__(256) void histC_k(const int* __restrict__ dst,
                                               unsigned* __restrict__ hist) {
  __shared__ unsigned lh[64];
  int tid = threadIdx.x;
  if (tid < 64) lh[tid] = 0;
  __syncthreads();
  int base = blockIdx.x * 2048;
#pragma unroll
  for (int k = 0; k < 8; ++k) {
    int e = base + k * 256 + tid;
    if (e < NE) atomicAdd(&lh[((unsigned)dst[e]) >> 10], 1u);
  }
  __syncthreads();
  if (tid < 64 && lh[tid]) atomicAdd(&hist[tid], lh[tid]);
}

__global__ __launch_bounds__(64) void scan64_k(const unsigned* __restrict__ hist,
                                               unsigned* __restrict__ bases,
                                               unsigned* __restrict__ gcur) {
  int tid = threadIdx.x;
  unsigned v = hist[tid], incl = v;
#pragma unroll
  for (int o = 1; o < 64; o <<= 1) {
    unsigned t = __shfl_up(incl, o);
    if (tid >= o) incl += t;
  }
  unsigned ex = incl - v;
  bases[tid] = ex;
  gcur[tid] = ex;
  if (tid == 63) bases[64] = incl;  // = NE
}

__global__ __launch_bounds__(256) void msplit_k(const int* __restrict__ src,
                                                const int* __restrict__ dst,
                                                unsigned* __restrict__ gcur,
                                                unsigned* __restrict__ bufA) {
  __shared__ unsigned lh[64], gb[64], lc[64];
  int tid = threadIdx.x;
  if (tid < 64) { lh[tid] = 0; lc[tid] = 0; }
  __syncthreads();
  int base = blockIdx.x * 2048;
  unsigned s[8], d[8];
  bool val[8];
#pragma unroll
  for (int k = 0; k < 8; ++k) {
    int e = base + k * 256 + tid;
    val[k] = (e < NE);
    s[k] = val[k] ? (unsigned)src[e] : 0u;
    d[k] = val[k] ? (unsigned)dst[e] : 0u;
    if (val[k]) atomicAdd(&lh[d[k] >> 10], 1u);
  }
  __syncthreads();
  if (tid < 64 && lh[tid]) gb[tid] = atomicAdd(&gcur[tid], lh[tid]);
  __syncthreads();
#pragma unroll
  for (int k = 0; k < 8; ++k) {
    if (val[k]) {
      unsigned b = d[k] >> 10;
      unsigned pos = atomicAdd(&lc[b], 1u);
      bufA[gb[b] + pos] = (s[k] & 0xFFFFu) | ((d[k] & 1023u) << 16);
    }
  }
}

// per-bucket finalize, 2 blocks/bucket (each handles 512 nodes of the 1024)
__global__ __launch_bounds__(1024) void passB2_k(const unsigned* __restrict__ bases,
                                                 const unsigned* __restrict__ bufA,
                                                 unsigned short* __restrict__ esrc,
                                                 unsigned* __restrict__ rowptr,
                                                 float* __restrict__ inv) {
  __shared__ unsigned cnt[1024], offs[1024], s_[1024];
  __shared__ unsigned short stage[18432];
  const int bk = blockIdx.x >> 1;
  const int half = blockIdx.x & 1;
  const int tid = threadIdx.x;
  const unsigned base0 = bases[bk];
  const unsigned end0 = bases[bk + 1];
  const unsigned bcnt = end0 - base0;

  cnt[tid] = 0;
  __syncthreads();
  for (unsigned i = tid; i < bcnt; i += 1024)
    atomicAdd(&cnt[bufA[base0 + i] >> 16], 1u);
  __syncthreads();

  unsigned c = cnt[tid];
  s_[tid] = c;
  __syncthreads();
  for (int o = 1; o < 1024; o <<= 1) {
    unsigned t = (tid >= o) ? s_[tid - o] : 0u;
    __syncthreads();
    s_[tid] += t;
    __syncthreads();
  }
  unsigned ex = s_[tid] - c;
  offs[tid] = ex;
  const int lo = half * 512;
  if (tid >= lo && tid < lo + 512) {
    int node = bk * 1024 + tid;
    if (node < NN) {
      rowptr[node] = base0 + ex;
      inv[node] = 1.0f / fmaxf((float)c, 1.0f);
    }
  }
  cnt[tid] = 0;  // -> cursor
  if (bk == NBC - 1 && half == 0 && tid == 0) rowptr[NN] = NE;
  __syncthreads();

  const unsigned hbase = offs[lo];  // entries before my half
  const unsigned hcnt = half ? (bcnt - offs[512]) : offs[512];

  if (hcnt <= 18432) {
    for (unsigned i = tid; i < bcnt; i += 1024) {
      unsigned w = bufA[base0 + i];
      unsigned dl = w >> 16;
      if ((int)(dl >> 9) == half) {
        unsigned pos = atomicAdd(&cnt[dl], 1u);
        stage[offs[dl] - hbase + pos] = (unsigned short)w;
      }
    }
    __syncthreads();
    for (unsigned i = tid; i < hcnt; i += 1024) esrc[base0 + hbase + i] = stage[i];
  } else {  // statistically impossible fallback
    for (unsigned i = tid; i < bcnt; i += 1024) {
      unsigned w = bufA[base0 + i];
      unsigned dl = w >> 16;
      if ((int)(dl >> 9) == half) {
        unsigned pos = atomicAdd(&cnt[dl], 1u);
        esrc[base0 + offs[dl] + pos] = (unsigned short)w;
      }
    }
  }
}

// ---------------- gathers: wave-per-node, batched u16 index loads ----------------
// Indices are wave-uniform; load 8 at once via one uint4 (16B, t aligned to 8)
// instead of 8 redundant u16 loads -> 16 VMEM ops per 8 edges becomes 9.
__global__ __launch_bounds__(256) void gather_mean_k(
    const unsigned short* __restrict__ esrc, const unsigned* __restrict__ rowptr,
    const float* __restrict__ inv, const unsigned* __restrict__ xb,
    unsigned* __restrict__ meanb) {
  int node = blockIdx.x * 4 + (threadIdx.x >> 6);
  if (node >= NN) return;
  int lane = threadIdx.x & 63;
  unsigned beg = rowptr[node], end = rowptr[node + 1];
  float ax = 0.f, ay = 0.f;
  unsigned t = beg;
  for (; t < end && (t & 7u); ++t) {  // align to 8 (<=7 iters)
    unsigned v0 = xb[(size_t)esrc[t] * 64 + lane];
    ax += bflo(v0); ay += bfhi(v0);
  }
  for (; t + 8 <= end; t += 8) {
    uint4 iw = *(const uint4*)(esrc + t);
    unsigned v0 = xb[(size_t)(iw.x & 0xFFFFu) * 64 + lane];
    unsigned v1 = xb[(size_t)(iw.x >> 16) * 64 + lane];
    unsigned v2 = xb[(size_t)(iw.y & 0xFFFFu) * 64 + lane];
    unsigned v3 = xb[(size_t)(iw.y >> 16) * 64 + lane];
    unsigned v4 = xb[(size_t)(iw.z & 0xFFFFu) * 64 + lane];
    unsigned v5 = xb[(size_t)(iw.z >> 16) * 64 + lane];
    unsigned v6 = xb[(size_t)(iw.w & 0xFFFFu) * 64 + lane];
    unsigned v7 = xb[(size_t)(iw.w >> 16) * 64 + lane];
    ax += ((bflo(v0) + bflo(v1)) + (bflo(v2) + bflo(v3))) +
          ((bflo(v4) + bflo(v5)) + (bflo(v6) + bflo(v7)));
    ay += ((bfhi(v0) + bfhi(v1)) + (bfhi(v2) + bfhi(v3))) +
          ((bfhi(v4) + bfhi(v5)) + (bfhi(v6) + bfhi(v7)));
  }
  if (t + 4 <= end) {  // t%8==0 -> 8B-aligned
    uint2 iw = *(const uint2*)(esrc + t);
    unsigned v0 = xb[(size_t)(iw.x & 0xFFFFu) * 64 + lane];
    unsigned v1 = xb[(size_t)(iw.x >> 16) * 64 + lane];
    unsigned v2 = xb[(size_t)(iw.y & 0xFFFFu) * 64 + lane];
    unsigned v3 = xb[(size_t)(iw.y >> 16) * 64 + lane];
    ax += (bflo(v0) + bflo(v1)) + (bflo(v2) + bflo(v3));
    ay += (bfhi(v0) + bfhi(v1)) + (bfhi(v2) + bfhi(v3));
    t += 4;
  }
  for (; t < end; ++t) {
    unsigned v0 = xb[(size_t)esrc[t] * 64 + lane];
    ax += bflo(v0); ay += bfhi(v0);
  }
  float sc = inv[node];
  meanb[(size_t)node * 64 + lane] =
      (unsigned)f2bf(ax * sc) | ((unsigned)f2bf(ay * sc) << 16);
}

__global__ __launch_bounds__(256) void gather_add_k(
    const unsigned short* __restrict__ esrc, const unsigned* __restrict__ rowptr,
    const float* __restrict__ inv, const unsigned* __restrict__ P,
    float* __restrict__ out) {
  int node = blockIdx.x * 4 + (threadIdx.x >> 6);
  if (node >= NN) return;
  int lane = threadIdx.x & 63;
  unsigned beg = rowptr[node], end = rowptr[node + 1];
  float ax = 0.f, ay = 0.f;
  unsigned t = beg;
  for (; t < end && (t & 7u); ++t) {
    unsigned v0 = P[(size_t)esrc[t] * 64 + lane];
    ax += bflo(v0); ay += bfhi(v0);
  }
  for (; t + 8 <= end; t += 8) {
    uint4 iw = *(const uint4*)(esrc + t);
    unsigned v0 = P[(size_t)(iw.x & 0xFFFFu) * 64 + lane];
    unsigned v1 = P[(size_t)(iw.x >> 16) * 64 + lane];
    unsigned v2 = P[(size_t)(iw.y & 0xFFFFu) * 64 + lane];
    unsigned v3 = P[(size_t)(iw.y >> 16) * 64 + lane];
    unsigned v4 = P[(size_t)(iw.z & 0xFFFFu) * 64 + lane];
    unsigned v5 = P[(size_t)(iw.z >> 16) * 64 + lane];
    unsigned v6 = P[(size_t)(iw.w & 0xFFFFu) * 64 + lane];
    unsigned v7 = P[(size_t)(iw.w >> 16) * 64 + lane];
    ax += ((bflo(v0) + bflo(v1)) + (bflo(v2) + bflo(v3))) +
          ((bflo(v4) + bflo(v5)) + (bflo(v6) + bflo(v7)));
    ay += ((bfhi(v0) + bfhi(v1)) + (bfhi(v2) + bfhi(v3))) +
          ((bfhi(v4) + bfhi(v5)) + (bfhi(v6) + bfhi(v7)));
  }
  if (t + 4 <= end) {
    uint2 iw = *(const uint2*)(esrc + t);
    unsigned v0 = P[(size_t)(iw.x & 0xFFFFu) * 64 + lane];
    unsigned v1 = P[(size_t)(iw.x >> 16) * 64 + lane];
    unsigned v2 = P[(size_t)(iw.y & 0xFFFFu) * 64 + lane];
    unsigned v3 = P[(size_t)(iw.y >> 16) * 64 + lane];
    ax += (bflo(v0) + bflo(v1)) + (bflo(v2) + bflo(v3));
    ay += (bfhi(v0) + bfhi(v1)) + (bfhi(v2) + bfhi(v3));
    t += 4;
  }
  for (; t < end; ++t) {
    unsigned v0 = P[(size_t)esrc[t] * 64 + lane];
    ax += bflo(v0); ay += bfhi(v0);
  }
  float sc = inv[node];
  float2* O = (float2*)out;
  float2 o = O[(size_t)node * 64 + lane];
  o.x += ax * sc;
  o.y += ay * sc;
  O[(size_t)node * 64 + lane] = o;
}

// ---------------- MFMA GEMMs: 64x64 tile, single-buffer LDS (r14/r19-proven) ----------------
__global__ __launch_bounds__(256) void mgemm1_k(
    const unsigned short* __restrict__ xb, const unsigned short* __restrict__ meanb,
    const unsigned short* __restrict__ W1t, const float* __restrict__ b1,
    unsigned short* __restrict__ h) {
  __shared__ __align__(16) char As[64 * 64 * 2];
  __shared__ __align__(16) char Bs[64 * 64 * 2];
  const int tid = threadIdx.x;
  const int lane = tid & 63, wid = tid >> 6;
  const int wm = (wid >> 1) * 32, wn = (wid & 1) * 32;
  const int r16 = lane & 15, g = lane >> 4;
  const unsigned bid = blockIdx.x;
  const unsigned v_ = (bid & 7u) * 391u + (bid >> 3);  // bijective: 3128 = 8*391
  const int m0 = (int)(v_ >> 2) * 64;
  const int j0 = (int)(v_ & 3u) * 64;
  const int wbase = (tid & ~63);

  const unsigned short* aSrcX[2];
  const unsigned short* aSrcM[2];
  const unsigned short* bSrc[2];
  char* ldsA[2];
  char* ldsB[2];
#pragma unroll
  for (int p = 0; p < 2; ++p) {
    int id = p * 256 + tid;
    int r = id >> 3, cb = id & 7;
    int grow = m0 + r;
    if (grow >= NN) grow = NN - 1;            // dead rows, masked at store
    int swz = (cb ^ (r & 7)) << 3;            // element offset of 16B chunk
    aSrcX[p] = xb + (size_t)grow * 128 + swz;
    aSrcM[p] = meanb + (size_t)grow * 128 + swz;
    bSrc[p] = W1t + (size_t)(j0 + r) * 256 + swz;
    ldsA[p] = As + ((p * 256 + wbase) << 4);
    ldsB[p] = Bs + ((p * 256 + wbase) << 4);
  }

  int aoff[2][2], boff[2][2];
#pragma unroll
  for (int f = 0; f < 2; ++f)
#pragma unroll
    for (int ks = 0; ks < 2; ++ks) {
      int ar = wm + f * 16 + r16;
      aoff[f][ks] = ar * 128 + ((ks * 64 + g * 16) ^ ((ar & 7) << 4));
      int br = wn + f * 16 + r16;
      boff[f][ks] = br * 128 + ((ks * 64 + g * 16) ^ ((br & 7) << 4));
    }

  f32x4 acc[2][2] = {};

  auto compute = [&]() {
#pragma unroll
    for (int ks = 0; ks < 2; ++ks) {
      short8 af[2], bf[2];
#pragma unroll
      for (int f = 0; f < 2; ++f) {
        af[f] = *(const short8*)(As + aoff[f][ks]);
        bf[f] = *(const short8*)(Bs + boff[f][ks]);
      }
#pragma unroll
      for (int i = 0; i < 2; ++i)
#pragma unroll
        for (int j = 0; j < 2; ++j)
          acc[i][j] = __builtin_amdgcn_mfma_f32_16x16x32_bf16(af[i], bf[j], acc[i][j], 0, 0, 0);
    }
  };

  // s=0: A from xb k0=0
  GLDS(aSrcX[0], ldsA[0]); GLDS(aSrcX[1], ldsA[1]);
  GLDS(bSrc[0], ldsB[0]);  GLDS(bSrc[1], ldsB[1]);

  // dropout scales overlap stage-0 flight (proven placement)
  float dsc[2][2][4];
#pragma unroll
  for (int i = 0; i < 2; ++i)
#pragma unroll
    for (int j = 0; j < 2; ++j) {
      int col = j0 + wn + j * 16 + r16;
#pragma unroll
      for (int q = 0; q < 4; ++q) {
        int row = m0 + wm + i * 16 + g * 4 + q;
        dsc[i][j][q] = dropout_scale((unsigned)row * 256u + (unsigned)col);
      }
    }

  __syncthreads();
  compute();
  __syncthreads();
  // s=1: A from xb k0=64
  GLDS(aSrcX[0] + 64, ldsA[0]); GLDS(aSrcX[1] + 64, ldsA[1]);
  GLDS(bSrc[0] + 64, ldsB[0]);  GLDS(bSrc[1] + 64, ldsB[1]);
  __syncthreads();
  compute();
  __syncthreads();
  // s=2: A from meanb k0=0
  GLDS(aSrcM[0], ldsA[0]);       GLDS(aSrcM[1], ldsA[1]);
  GLDS(bSrc[0] + 128, ldsB[0]);  GLDS(bSrc[1] + 128, ldsB[1]);
  __syncthreads();
  compute();
  __syncthreads();
  // s=3: A from meanb k0=64
  GLDS(aSrcM[0] + 64, ldsA[0]);  GLDS(aSrcM[1] + 64, ldsA[1]);
  GLDS(bSrc[0] + 192, ldsB[0]);  GLDS(bSrc[1] + 192, ldsB[1]);
  __syncthreads();
  compute();

#pragma unroll
  for (int i = 0; i < 2; ++i)
#pragma unroll
    for (int j = 0; j < 2; ++j) {
      int col = j0 + wn + j * 16 + r16;
      float bias = b1[col];
#pragma unroll
      for (int q = 0; q < 4; ++q) {
        int row = m0 + wm + i * 16 + g * 4 + q;
        if (row < NN) {
          float v = fmaxf(acc[i][j][q] + bias, 0.f) * dsc[i][j][q];
          h[(size_t)row * 256 + col] = f2bf(v);
        }
      }
    }
}

__global__ __launch_bounds__(256) void mgemm2_k(
    const unsigned short* __restrict__ h, const unsigned short* __restrict__ W2t,
    const float* __restrict__ b2, unsigned short* __restrict__ P,
    float* __restrict__ out) {
  __shared__ __align__(16) char As[64 * 64 * 2];
  __shared__ __align__(16) char Bs[64 * 64 * 2];
  const int tid = threadIdx.x;
  const int lane = tid & 63, wid = tid >> 6;
  const int wm = (wid >> 1) * 32, wn = (wid & 1) * 32;
  const int r16 = lane & 15, g = lane >> 4;
  const unsigned bid = blockIdx.x;
  const unsigned v_ = (bid & 7u) * 391u + (bid >> 3);
  const int m0 = (int)(v_ >> 2) * 64;
  const int j0 = (int)(v_ & 3u) * 64;
  const int wbase = (tid & ~63);

  const unsigned short* aSrc[2];
  const unsigned short* bSrc[2];
  char* ldsA[2];
  char* ldsB[2];
#pragma unroll
  for (int p = 0; p < 2; ++p) {
    int id = p * 256 + tid;
    int r = id >> 3, cb = id & 7;
    int grow = m0 + r;
    if (grow >= NN) grow = NN - 1;
    int swz = (cb ^ (r & 7)) << 3;
    aSrc[p] = h + (size_t)grow * 256 + swz;
    bSrc[p] = W2t + (size_t)(j0 + r) * 256 + swz;
    ldsA[p] = As + ((p * 256 + wbase) << 4);
    ldsB[p] = Bs + ((p * 256 + wbase) << 4);
  }

  int aoff[2][2], boff[2][2];
#pragma unroll
  for (int f = 0; f < 2; ++f)
#pragma unroll
    for (int ks = 0; ks < 2; ++ks) {
      int ar = wm + f * 16 + r16;
      aoff[f][ks] = ar * 128 + ((ks * 64 + g * 16) ^ ((ar & 7) << 4));
      int br = wn + f * 16 + r16;
      boff[f][ks] = br * 128 + ((ks * 64 + g * 16) ^ ((br & 7) << 4));
    }

  f32x4 acc[2][2] = {};

  auto compute = [&]() {
#pragma unroll
    for (int ks = 0; ks < 2; ++ks) {
      short8 af[2], bf[2];
#pragma unroll
      for (int f = 0; f < 2; ++f) {
        af[f] = *(const short8*)(As + aoff[f][ks]);
        bf[f] = *(const short8*)(Bs + boff[f][ks]);
      }
#pragma unroll
      for (int i = 0; i < 2; ++i)
#pragma unroll
        for (int j = 0; j < 2; ++j)
          acc[i][j] = __builtin_amdgcn_mfma_f32_16x16x32_bf16(af[i], bf[j], acc[i][j], 0, 0, 0);
    }
  };

  GLDS(aSrc[0], ldsA[0]); GLDS(aSrc[1], ldsA[1]);
  GLDS(bSrc[0], ldsB[0]); GLDS(bSrc[1], ldsB[1]);
  __syncthreads();
  compute();
  __syncthreads();
  GLDS(aSrc[0] + 64, ldsA[0]); GLDS(aSrc[1] + 64, ldsA[1]);
  GLDS(bSrc[0] + 64, ldsB[0]); GLDS(bSrc[1] + 64, ldsB[1]);
  __syncthreads();
  compute();
  __syncthreads();
  GLDS(aSrc[0] + 128, ldsA[0]); GLDS(aSrc[1] + 128, ldsA[1]);
  GLDS(bSrc[0] + 128, ldsB[0]); GLDS(bSrc[1] + 128, ldsB[1]);
  __syncthreads();
  compute();
  __syncthreads();
  GLDS(aSrc[0] + 192, ldsA[0]); GLDS(aSrc[1] + 192, ldsA[1]);
  GLDS(bSrc[0] + 192, ldsB[0]); GLDS(bSrc[1] + 192, ldsB[1]);
  __syncthreads();
  compute();

#pragma unroll
  for (int i = 0; i < 2; ++i)
#pragma unroll
    for (int j = 0; j < 2; ++j) {
      int col = j0 + wn + j * 16 + r16;  // global col in [0,256)
#pragma unroll
      for (int q = 0; q < 4; ++q) {
        int row = m0 + wm + i * 16 + g * 4 + q;
        if (row < NN) {
          if (col < 128) {
            P[(size_t)row * 128 + col] = f2bf(acc[i][j][q]);
          } else {
            out[(size_t)row * 128 + (col - 128)] = acc[i][j][q] + b2[col - 128];
          }
        }
      }
    }
}

// ---------------- launch ----------------
extern "C" void kernel_launch(void* const* d_in, const int* in_sizes, int n_in,
                              void* d_out, int out_size, void* d_ws, size_t ws_size,
                              hipStream_t stream) {
  const float* x   = (const float*)d_in[0];
  const int*   ei  = (const int*)d_in[1];
  const float* Wl1 = (const float*)d_in[2];
  const float* Wr1 = (const float*)d_in[3];
  const float* b1  = (const float*)d_in[4];
  const float* Wl2 = (const float*)d_in[5];
  const float* Wr2 = (const float*)d_in[6];
  const float* b2  = (const float*)d_in[7];
  float* out = (float*)d_out;

  const int* src = ei;
  const int* dst = ei + NE;

  // workspace layout — NO OVERLAPS, peak ~74 MB:
  char* ws = (char*)d_ws;
  unsigned*       rowptr = (unsigned*)ws;                      // 0x0       + 200,004
  float*          inv    = (float*)(ws + 0x40000);             // 0x40000   + 200,000
  unsigned*       hist   = (unsigned*)(ws + 0x80000);          // 0x80000   + 256
  unsigned*       bases  = (unsigned*)(ws + 0x80400);          // 0x80400   + 260
  unsigned*       gcur   = (unsigned*)(ws + 0x80800);          // 0x80800   + 256
  unsigned short* esrc   = (unsigned short*)(ws + 0xC0000);    // 0xC0000   + 1.6MB
  unsigned*       bufA   = (unsigned*)(ws + 0x280000);         // 0x280000  + 3.2MB
  unsigned short* W1t    = (unsigned short*)(ws + 0x600000);   // 0x600000  + 0x20000
  unsigned short* W2t    = (unsigned short*)(ws + 0x620000);   // 0x620000  + 0x20000
  unsigned short* xb     = (unsigned short*)(ws + 0x700000);   // 0x700000  + 0xC35000
  unsigned short* meanb  = (unsigned short*)(ws + 0x1400000);  // 0x1400000 + 0xC35000
  unsigned short* h      = (unsigned short*)(ws + 0x2100000);  // 0x2100000 + 0x186A000
  unsigned short* P      = (unsigned short*)(ws + 0x3A00000);  // 0x3A00000 + 0xC35000

  const int TPB = 256;

  // prep (fused cvtx + mkw + hist zero) — no graph memset nodes
  prep_k<<<CVTB + 513, TPB, 0, stream>>>((const float4*)x, (uint2*)xb,
                                         Wl1, Wr1, Wl2, Wr2, W1t, W2t, hist);

  // CSR build: multi-split counting sort
  histC_k<<<MSB, TPB, 0, stream>>>(dst, hist);
  scan64_k<<<1, 64, 0, stream>>>(hist, bases, gcur);
  msplit_k<<<MSB, TPB, 0, stream>>>(src, dst, gcur, bufA);
  passB2_k<<<NBC * 2, 1024, 0, stream>>>(bases, bufA, esrc, rowptr, inv);

  // layer 1
  gather_mean_k<<<(NN + 3) / 4, TPB, 0, stream>>>(esrc, rowptr, inv, (const unsigned*)xb, (unsigned*)meanb);
  mgemm1_k<<<3128, TPB, 0, stream>>>(xb, meanb, W1t, b1, h);

  // layer 2
  mgemm2_k<<<3128, TPB, 0, stream>>>(h, W2t, b2, P, out);
  gather_add_k<<<(NN + 3) / 4, TPB, 0, stream>>>(esrc, rowptr, inv, (const unsigned*)P, out);
}

// Round 23
// 169.382 us; speedup vs baseline: 1.1319x; 1.1319x over previous
//
#include <hip/hip_runtime.h>

#define NN 50000
#define NE 800000
#define NBC 49            // coarse buckets of 1024 dst nodes
#define MSB 391           // msplit/hist blocks (x2048 edges)

typedef __attribute__((ext_vector_type(8))) short short8;
typedef __attribute__((ext_vector_type(4))) float f32x4;

// global -> LDS direct DMA, 16B/lane, offset ALWAYS 0 (non-zero offset
// immediate is broken for this builtin — proven by round-13/14 bisection)
#define GLDS(g, l)                                                              \
  __builtin_amdgcn_global_load_lds(                                             \
      (const __attribute__((address_space(1))) void*)(g),                       \
      (__attribute__((address_space(3))) void*)(l), 16, 0, 0)

// ---------------- bf16 helpers (RNE) ----------------
__device__ __forceinline__ unsigned short f2bf(float f) {
  union { float f; unsigned u; } v; v.f = f;
  unsigned r = (v.u + 0x7FFFu + ((v.u >> 16) & 1u)) >> 16;
  return (unsigned short)r;
}
__device__ __forceinline__ float bflo(unsigned u) {
  union { unsigned x; float f; } v; v.x = u << 16; return v.f;
}
__device__ __forceinline__ float bfhi(unsigned u) {
  union { unsigned x; float f; } v; v.x = u & 0xFFFF0000u; return v.f;
}

// ---------------- fp8 e4m3 encode (RNE, subnormal-correct) ----------------
// e4m3: sign(1) exp(4,bias7) mant(3); min normal 2^-6, subnormal step 2^-9.
// RNE truncating 20 bits: constant is (1<<19)-1 = 0x7FFFF  (r22 bug: 0xFFFFF
// was ceiling-on-magnitude -> systematic +bias; fixed here).
__device__ __forceinline__ unsigned char f2e4m3(float f) {
  unsigned u; __builtin_memcpy(&u, &f, 4);
  unsigned s = (u >> 24) & 0x80u;
  float av = fabsf(f);
  if (av < 0.015625f) {                       // subnormal: round(av*512) in 0..8
    int sub = (int)rintf(av * 512.0f);        // ==8 -> code 8 == min normal 2^-6
    return (unsigned char)(s | (unsigned)sub);
  }
  unsigned m = u & 0x7FFFFFFFu;
  unsigned r = (m + 0x7FFFFu + ((m >> 20) & 1u)) >> 20;  // correct RNE at bit20
  int e8 = (int)(r >> 3) - 120;               // re-bias 127->7
  if (e8 > 15) return (unsigned char)(s | 0x7Eu);  // clamp (unreachable here)
  return (unsigned char)(s | ((unsigned)e8 << 3) | (r & 7u));
}

// ---------------- threefry2x32, JAX partitionable, key = (0, 42) ----------------
__device__ __forceinline__ unsigned tf_rotl(unsigned x, int r) {
#if __has_builtin(__builtin_amdgcn_alignbit)
  return __builtin_amdgcn_alignbit(x, x, 32 - r);
#else
  return (x << r) | (x >> (32 - r));
#endif
}
__device__ __forceinline__ void threefry_0_42(unsigned x0, unsigned x1,
                                              unsigned& o0, unsigned& o1) {
  const unsigned k0 = 0u, k1 = 42u;
  const unsigned k2 = k0 ^ k1 ^ 0x1BD11BDAu;
  x0 += k0; x1 += k1;
#define TF_R(r) { x0 += x1; x1 = tf_rotl(x1, (r)); x1 ^= x0; }
  TF_R(13) TF_R(15) TF_R(26) TF_R(6)
  x0 += k1; x1 += k2 + 1u;
  TF_R(17) TF_R(29) TF_R(16) TF_R(24)
  x0 += k2; x1 += k0 + 2u;
  TF_R(13) TF_R(15) TF_R(26) TF_R(6)
  x0 += k0; x1 += k1 + 3u;
  TF_R(17) TF_R(29) TF_R(16) TF_R(24)
  x0 += k1; x1 += k2 + 4u;
  TF_R(13) TF_R(15) TF_R(26) TF_R(6)
  x0 += k2; x1 += k0 + 5u;
#undef TF_R
  o0 = x0; o1 = x1;
}
// keep iff uniform<0.9f; 0.9f == 7549747/2^23 exactly -> integer compare
__device__ __forceinline__ float dropout_scale(unsigned flat) {
  unsigned o0, o1;
  threefry_0_42(0u, flat, o0, o1);
  unsigned bits = o0 ^ o1;
  return ((bits >> 9) < 7549747u) ? (1.0f / 0.9f) : 0.0f;
}

// ---------------- fused prep: x->bf16 + weight packing + hist zero ----------------
#define CVTB 6250  // 1.6M float4 / 256
__global__ void prep_k(const float4* __restrict__ x, uint2* __restrict__ xb,
                       const float* __restrict__ Wl1, const float* __restrict__ Wr1,
                       const float* __restrict__ Wl2, const float* __restrict__ Wr2,
                       unsigned short* __restrict__ W1t, unsigned short* __restrict__ W2t,
                       unsigned* __restrict__ hist) {
  int bid = blockIdx.x;
  if (bid < CVTB) {
    int i = bid * 256 + threadIdx.x;
    float4 v = x[i];
    uint2 o;
    o.x = (unsigned)f2bf(v.x) | ((unsigned)f2bf(v.y) << 16);
    o.y = (unsigned)f2bf(v.z) | ((unsigned)f2bf(v.w) << 16);
    xb[i] = o;
  } else if (bid < CVTB + 512) {
    int gid = (bid - CVTB) * 256 + threadIdx.x;  // 131072
    int idx = gid & 65535;
    int n = idx >> 8, k = idx & 255;
    if (gid < 65536) {
      float v = (k < 128) ? Wr1[(size_t)k * 256 + n] : Wl1[(size_t)(k - 128) * 256 + n];
      W1t[idx] = f2bf(v);
    } else {
      float v = (n < 128) ? Wl2[(size_t)k * 128 + n] : Wr2[(size_t)k * 128 + (n - 128)];
      W2t[idx] = f2bf(v);
    }
  } else {
    if (threadIdx.x < 64) hist[threadIdx.x] = 0;
  }
}

// ---------------- CSR build: multi-split counting sort (r14/r19-proven) ----------------
__global__ __launch_bounds__(256) void histC_k(const int* __restrict__ dst,
                                               unsigned* __restrict__ hist) {
  __shared__ unsigned lh[64];
  int tid = threadIdx.x;
  if (tid < 64) lh[tid] = 0;
  __syncthreads();
  int base = blockIdx.x * 2048;
#pragma unroll
  for (int k = 0; k < 8; ++k) {
    int e = base + k * 256 + tid;
    if (e < NE) atomicAdd(&lh[((unsigned)dst[e]) >> 10], 1u);
  }
  __syncthreads();
  if (tid < 64 && lh[tid]) atomicAdd(&hist[tid], lh[tid]);
}

__global__ __launch_bounds__(64) void scan64_k(const unsigned* __restrict__ hist,
                                               unsigned* __restrict__ bases,
                                               unsigned* __restrict__ gcur) {
  int tid = threadIdx.x;
  unsigned v = hist[tid], incl = v;
#pragma unroll
  for (int o = 1; o < 64; o <<= 1) {
    unsigned t = __shfl_up(incl, o);
    if (tid >= o) incl += t;
  }
  unsigned ex = incl - v;
  bases[tid] = ex;
  gcur[tid] = ex;
  if (tid == 63) bases[64] = incl;  // = NE
}

__global__ __launch_bounds__(256) void msplit_k(const int* __restrict__ src,
                                                const int* __restrict__ dst,
                                                unsigned* __restrict__ gcur,
                                                unsigned* __restrict__ bufA) {
  __shared__ unsigned lh[64], gb[64], lc[64];
  int tid = threadIdx.x;
  if (tid < 64) { lh[tid] = 0; lc[tid] = 0; }
  __syncthreads();
  int base = blockIdx.x * 2048;
  unsigned s[8], d[8];
  bool val[8];
#pragma unroll
  for (int k = 0; k < 8; ++k) {
    int e = base + k * 256 + tid;
    val[k] = (e < NE);
    s[k] = val[k] ? (unsigned)src[e] : 0u;
    d[k] = val[k] ? (unsigned)dst[e] : 0u;
    if (val[k]) atomicAdd(&lh[d[k] >> 10], 1u);
  }
  __syncthreads();
  if (tid < 64 && lh[tid]) gb[tid] = atomicAdd(&gcur[tid], lh[tid]);
  __syncthreads();
#pragma unroll
  for (int k = 0; k < 8; ++k) {
    if (val[k]) {
      unsigned b = d[k] >> 10;
      unsigned pos = atomicAdd(&lc[b], 1u);
      bufA[gb[b] + pos] = (s[k] & 0xFFFFu) | ((d[k] & 1023u) << 16);
    }
  }
}

__global__ __launch_bounds__(1024) void passB2_k(const unsigned* __restrict__ bases,
                                                 const unsigned* __restrict__ bufA,
                                                 unsigned short* __restrict__ esrc,
                                                 unsigned* __restrict__ rowptr,
                                                 float* __restrict__ inv) {
  __shared__ unsigned cnt[1024], offs[1024], s_[1024];
  __shared__ unsigned short stage[18432];
  const int b = blockIdx.x, tid = threadIdx.x;
  const unsigned base0 = bases[b];
  const unsigned end0 = bases[b + 1];
  const unsigned bcnt = end0 - base0;

  cnt[tid] = 0;
  __syncthreads();
  for (unsigned i = tid; i < bcnt; i += 1024)
    atomicAdd(&cnt[bufA[base0 + i] >> 16], 1u);
  __syncthreads();

  unsigned c = cnt[tid];
  s_[tid] = c;
  __syncthreads();
  for (int o = 1; o < 1024; o <<= 1) {
    unsigned t = (tid >= o) ? s_[tid - o] : 0u;
    __syncthreads();
    s_[tid] += t;
    __syncthreads();
  }
  unsigned ex = s_[tid] - c;
  offs[tid] = ex;
  int node = b * 1024 + tid;
  if (node < NN) {
    rowptr[node] = base0 + ex;
    inv[node] = 1.0f / fmaxf((float)c, 1.0f);
  }
  cnt[tid] = 0;  // -> cursor
  if (b == NBC - 1 && tid == 0) rowptr[NN] = NE;
  __syncthreads();

  if (bcnt <= 18432) {
    for (unsigned i = tid; i < bcnt; i += 1024) {
      unsigned w = bufA[base0 + i];
      unsigned dl = w >> 16;
      unsigned pos = atomicAdd(&cnt[dl], 1u);
      stage[offs[dl] + pos] = (unsigned short)w;
    }
    __syncthreads();
    for (unsigned i = tid; i < bcnt; i += 1024) esrc[base0 + i] = stage[i];
  } else {
    for (unsigned i = tid; i < bcnt; i += 1024) {
      unsigned w = bufA[base0 + i];
      unsigned dl = w >> 16;
      unsigned pos = atomicAdd(&cnt[dl], 1u);
      esrc[base0 + offs[dl] + pos] = (unsigned short)w;
    }
  }
}

// ---------------- gathers: wave-per-node full row, 8-deep MLP (r19-proven) ----------------
__global__ __launch_bounds__(256) void gather_mean_k(
    const unsigned short* __restrict__ esrc, const unsigned* __restrict__ rowptr,
    const float* __restrict__ inv, const unsigned* __restrict__ xb,
    unsigned* __restrict__ meanb) {
  int node = blockIdx.x * 4 + (threadIdx.x >> 6);
  if (node >= NN) return;
  int lane = threadIdx.x & 63;
  unsigned beg = rowptr[node], end = rowptr[node + 1];
  float ax = 0.f, ay = 0.f;
  unsigned t = beg;
  for (; t + 8 <= end; t += 8) {
    unsigned v0 = xb[(size_t)esrc[t + 0] * 64 + lane];
    unsigned v1 = xb[(size_t)esrc[t + 1] * 64 + lane];
    unsigned v2 = xb[(size_t)esrc[t + 2] * 64 + lane];
    unsigned v3 = xb[(size_t)esrc[t + 3] * 64 + lane];
    unsigned v4 = xb[(size_t)esrc[t + 4] * 64 + lane];
    unsigned v5 = xb[(size_t)esrc[t + 5] * 64 + lane];
    unsigned v6 = xb[(size_t)esrc[t + 6] * 64 + lane];
    unsigned v7 = xb[(size_t)esrc[t + 7] * 64 + lane];
    ax += ((bflo(v0) + bflo(v1)) + (bflo(v2) + bflo(v3))) +
          ((bflo(v4) + bflo(v5)) + (bflo(v6) + bflo(v7)));
    ay += ((bfhi(v0) + bfhi(v1)) + (bfhi(v2) + bfhi(v3))) +
          ((bfhi(v4) + bfhi(v5)) + (bfhi(v6) + bfhi(v7)));
  }
  for (; t + 4 <= end; t += 4) {
    unsigned v0 = xb[(size_t)esrc[t + 0] * 64 + lane];
    unsigned v1 = xb[(size_t)esrc[t + 1] * 64 + lane];
    unsigned v2 = xb[(size_t)esrc[t + 2] * 64 + lane];
    unsigned v3 = xb[(size_t)esrc[t + 3] * 64 + lane];
    ax += (bflo(v0) + bflo(v1)) + (bflo(v2) + bflo(v3));
    ay += (bfhi(v0) + bfhi(v1)) + (bfhi(v2) + bfhi(v3));
  }
  for (; t < end; ++t) {
    unsigned v0 = xb[(size_t)esrc[t] * 64 + lane];
    ax += bflo(v0); ay += bfhi(v0);
  }
  float sc = inv[node];
  meanb[(size_t)node * 64 + lane] =
      (unsigned)f2bf(ax * sc) | ((unsigned)f2bf(ay * sc) << 16);
}

// gather_add over fp8(e4m3) P: lane reads u16 = 2 fp8; decode via LDS table
// (1KB, built once per block before node early-exit, broadcast-friendly).
__global__ __launch_bounds__(256) void gather_add_k(
    const unsigned short* __restrict__ esrc, const unsigned* __restrict__ rowptr,
    const float* __restrict__ inv, const unsigned short* __restrict__ P8,
    float* __restrict__ out) {
  __shared__ float tab[256];
  {
    int i = threadIdx.x;
    unsigned em = i & 0x7F;
    float v;
    if (em < 8) {
      v = (float)em * 0.001953125f;  // subnormal: em * 2^-9
    } else {
      unsigned bits = (((em >> 3) + 120u) << 23) | ((em & 7u) << 20);
      __builtin_memcpy(&v, &bits, 4);
    }
    tab[i] = (i & 0x80) ? -v : v;
  }
  __syncthreads();

  int node = blockIdx.x * 4 + (threadIdx.x >> 6);
  if (node >= NN) return;
  int lane = threadIdx.x & 63;
  unsigned beg = rowptr[node], end = rowptr[node + 1];
  float ax = 0.f, ay = 0.f;
  unsigned t = beg;
  for (; t + 8 <= end; t += 8) {
    unsigned w0 = P8[(size_t)esrc[t + 0] * 64 + lane];
    unsigned w1 = P8[(size_t)esrc[t + 1] * 64 + lane];
    unsigned w2 = P8[(size_t)esrc[t + 2] * 64 + lane];
    unsigned w3 = P8[(size_t)esrc[t + 3] * 64 + lane];
    unsigned w4 = P8[(size_t)esrc[t + 4] * 64 + lane];
    unsigned w5 = P8[(size_t)esrc[t + 5] * 64 + lane];
    unsigned w6 = P8[(size_t)esrc[t + 6] * 64 + lane];
    unsigned w7 = P8[(size_t)esrc[t + 7] * 64 + lane];
    ax += ((tab[w0 & 0xFFu] + tab[w1 & 0xFFu]) + (tab[w2 & 0xFFu] + tab[w3 & 0xFFu])) +
          ((tab[w4 & 0xFFu] + tab[w5 & 0xFFu]) + (tab[w6 & 0xFFu] + tab[w7 & 0xFFu]));
    ay += ((tab[w0 >> 8] + tab[w1 >> 8]) + (tab[w2 >> 8] + tab[w3 >> 8])) +
          ((tab[w4 >> 8] + tab[w5 >> 8]) + (tab[w6 >> 8] + tab[w7 >> 8]));
  }
  for (; t + 4 <= end; t += 4) {
    unsigned w0 = P8[(size_t)esrc[t + 0] * 64 + lane];
    unsigned w1 = P8[(size_t)esrc[t + 1] * 64 + lane];
    unsigned w2 = P8[(size_t)esrc[t + 2] * 64 + lane];
    unsigned w3 = P8[(size_t)esrc[t + 3] * 64 + lane];
    ax += (tab[w0 & 0xFFu] + tab[w1 & 0xFFu]) + (tab[w2 & 0xFFu] + tab[w3 & 0xFFu]);
    ay += (tab[w0 >> 8] + tab[w1 >> 8]) + (tab[w2 >> 8] + tab[w3 >> 8]);
  }
  for (; t < end; ++t) {
    unsigned w0 = P8[(size_t)esrc[t] * 64 + lane];
    ax += tab[w0 & 0xFFu];
    ay += tab[w0 >> 8];
  }
  float sc = inv[node];
  float2* O = (float2*)out;
  float2 o = O[(size_t)node * 64 + lane];
  o.x += ax * sc;
  o.y += ay * sc;
  O[(size_t)node * 64 + lane] = o;
}

// ---------------- MFMA GEMMs: 64x64 tile, single-buffer LDS (r14/r19-proven) ----------------
__global__ __launch_bounds__(256) void mgemm1_k(
    const unsigned short* __restrict__ xb, const unsigned short* __restrict__ meanb,
    const unsigned short* __restrict__ W1t, const float* __restrict__ b1,
    unsigned short* __restrict__ h) {
  __shared__ __align__(16) char As[64 * 64 * 2];
  __shared__ __align__(16) char Bs[64 * 64 * 2];
  const int tid = threadIdx.x;
  const int lane = tid & 63, wid = tid >> 6;
  const int wm = (wid >> 1) * 32, wn = (wid & 1) * 32;
  const int r16 = lane & 15, g = lane >> 4;
  const unsigned bid = blockIdx.x;
  const unsigned v_ = (bid & 7u) * 391u + (bid >> 3);  // bijective: 3128 = 8*391
  const int m0 = (int)(v_ >> 2) * 64;
  const int j0 = (int)(v_ & 3u) * 64;
  const int wbase = (tid & ~63);

  const unsigned short* aSrcX[2];
  const unsigned short* aSrcM[2];
  const unsigned short* bSrc[2];
  char* ldsA[2];
  char* ldsB[2];
#pragma unroll
  for (int p = 0; p < 2; ++p) {
    int id = p * 256 + tid;
    int r = id >> 3, cb = id & 7;
    int grow = m0 + r;
    if (grow >= NN) grow = NN - 1;            // dead rows, masked at store
    int swz = (cb ^ (r & 7)) << 3;            // element offset of 16B chunk
    aSrcX[p] = xb + (size_t)grow * 128 + swz;
    aSrcM[p] = meanb + (size_t)grow * 128 + swz;
    bSrc[p] = W1t + (size_t)(j0 + r) * 256 + swz;
    ldsA[p] = As + ((p * 256 + wbase) << 4);
    ldsB[p] = Bs + ((p * 256 + wbase) << 4);
  }

  int aoff[2][2], boff[2][2];
#pragma unroll
  for (int f = 0; f < 2; ++f)
#pragma unroll
    for (int ks = 0; ks < 2; ++ks) {
      int ar = wm + f * 16 + r16;
      aoff[f][ks] = ar * 128 + ((ks * 64 + g * 16) ^ ((ar & 7) << 4));
      int br = wn + f * 16 + r16;
      boff[f][ks] = br * 128 + ((ks * 64 + g * 16) ^ ((br & 7) << 4));
    }

  f32x4 acc[2][2] = {};

  auto compute = [&]() {
#pragma unroll
    for (int ks = 0; ks < 2; ++ks) {
      short8 af[2], bf[2];
#pragma unroll
      for (int f = 0; f < 2; ++f) {
        af[f] = *(const short8*)(As + aoff[f][ks]);
        bf[f] = *(const short8*)(Bs + boff[f][ks]);
      }
#pragma unroll
      for (int i = 0; i < 2; ++i)
#pragma unroll
        for (int j = 0; j < 2; ++j)
          acc[i][j] = __builtin_amdgcn_mfma_f32_16x16x32_bf16(af[i], bf[j], acc[i][j], 0, 0, 0);
    }
  };

  // s=0: A from xb k0=0
  GLDS(aSrcX[0], ldsA[0]); GLDS(aSrcX[1], ldsA[1]);
  GLDS(bSrc[0], ldsB[0]);  GLDS(bSrc[1], ldsB[1]);

  // dropout scales overlap stage-0 flight (proven placement)
  float dsc[2][2][4];
#pragma unroll
  for (int i = 0; i < 2; ++i)
#pragma unroll
    for (int j = 0; j < 2; ++j) {
      int col = j0 + wn + j * 16 + r16;
#pragma unroll
      for (int q = 0; q < 4; ++q) {
        int row = m0 + wm + i * 16 + g * 4 + q;
        dsc[i][j][q] = dropout_scale((unsigned)row * 256u + (unsigned)col);
      }
    }

  __syncthreads();
  compute();
  __syncthreads();
  // s=1: A from xb k0=64
  GLDS(aSrcX[0] + 64, ldsA[0]); GLDS(aSrcX[1] + 64, ldsA[1]);
  GLDS(bSrc[0] + 64, ldsB[0]);  GLDS(bSrc[1] + 64, ldsB[1]);
  __syncthreads();
  compute();
  __syncthreads();
  // s=2: A from meanb k0=0
  GLDS(aSrcM[0], ldsA[0]);       GLDS(aSrcM[1], ldsA[1]);
  GLDS(bSrc[0] + 128, ldsB[0]);  GLDS(bSrc[1] + 128, ldsB[1]);
  __syncthreads();
  compute();
  __syncthreads();
  // s=3: A from meanb k0=64
  GLDS(aSrcM[0] + 64, ldsA[0]);  GLDS(aSrcM[1] + 64, ldsA[1]);
  GLDS(bSrc[0] + 192, ldsB[0]);  GLDS(bSrc[1] + 192, ldsB[1]);
  __syncthreads();
  compute();

#pragma unroll
  for (int i = 0; i < 2; ++i)
#pragma unroll
    for (int j = 0; j < 2; ++j) {
      int col = j0 + wn + j * 16 + r16;
      float bias = b1[col];
#pragma unroll
      for (int q = 0; q < 4; ++q) {
        int row = m0 + wm + i * 16 + g * 4 + q;
        if (row < NN) {
          float v = fmaxf(acc[i][j][q] + bias, 0.f) * dsc[i][j][q];
          h[(size_t)row * 256 + col] = f2bf(v);
        }
      }
    }
}

__global__ __launch_bounds__(256) void mgemm2_k(
    const unsigned short* __restrict__ h, const unsigned short* __restrict__ W2t,
    const float* __restrict__ b2, unsigned char* __restrict__ P8,
    float* __restrict__ out) {
  __shared__ __align__(16) char As[64 * 64 * 2];
  __shared__ __align__(16) char Bs[64 * 64 * 2];
  const int tid = threadIdx.x;
  const int lane = tid & 63, wid = tid >> 6;
  const int wm = (wid >> 1) * 32, wn = (wid & 1) * 32;
  const int r16 = lane & 15, g = lane >> 4;
  const unsigned bid = blockIdx.x;
  const unsigned v_ = (bid & 7u) * 391u + (bid >> 3);
  const int m0 = (int)(v_ >> 2) * 64;
  const int j0 = (int)(v_ & 3u) * 64;
  const int wbase = (tid & ~63);

  const unsigned short* aSrc[2];
  const unsigned short* bSrc[2];
  char* ldsA[2];
  char* ldsB[2];
#pragma unroll
  for (int p = 0; p < 2; ++p) {
    int id = p * 256 + tid;
    int r = id >> 3, cb = id & 7;
    int grow = m0 + r;
    if (grow >= NN) grow = NN - 1;
    int swz = (cb ^ (r & 7)) << 3;
    aSrc[p] = h + (size_t)grow * 256 + swz;
    bSrc[p] = W2t + (size_t)(j0 + r) * 256 + swz;
    ldsA[p] = As + ((p * 256 + wbase) << 4);
    ldsB[p] = Bs + ((p * 256 + wbase) << 4);
  }

  int aoff[2][2], boff[2][2];
#pragma unroll
  for (int f = 0; f < 2; ++f)
#pragma unroll
    for (int ks = 0; ks < 2; ++ks) {
      int ar = wm + f * 16 + r16;
      aoff[f][ks] = ar * 128 + ((ks * 64 + g * 16) ^ ((ar & 7) << 4));
      int br = wn + f * 16 + r16;
      boff[f][ks] = br * 128 + ((ks * 64 + g * 16) ^ ((br & 7) << 4));
    }

  f32x4 acc[2][2] = {};

  auto compute = [&]() {
#pragma unroll
    for (int ks = 0; ks < 2; ++ks) {
      short8 af[2], bf[2];
#pragma unroll
      for (int f = 0; f < 2; ++f) {
        af[f] = *(const short8*)(As + aoff[f][ks]);
        bf[f] = *(const short8*)(Bs + boff[f][ks]);
      }
#pragma unroll
      for (int i = 0; i < 2; ++i)
#pragma unroll
        for (int j = 0; j < 2; ++j)
          acc[i][j] = __builtin_amdgcn_mfma_f32_16x16x32_bf16(af[i], bf[j], acc[i][j], 0, 0, 0);
    }
  };

  GLDS(aSrc[0], ldsA[0]); GLDS(aSrc[1], ldsA[1]);
  GLDS(bSrc[0], ldsB[0]); GLDS(bSrc[1], ldsB[1]);
  __syncthreads();
  compute();
  __syncthreads();
  GLDS(aSrc[0] + 64, ldsA[0]); GLDS(aSrc[1] + 64, ldsA[1]);
  GLDS(bSrc[0] + 64, ldsB[0]); GLDS(bSrc[1] + 64, ldsB[1]);
  __syncthreads();
  compute();
  __syncthreads();
  GLDS(aSrc[0] + 128, ldsA[0]); GLDS(aSrc[1] + 128, ldsA[1]);
  GLDS(bSrc[0] + 128, ldsB[0]); GLDS(bSrc[1] + 128, ldsB[1]);
  __syncthreads();
  compute();
  __syncthreads();
  GLDS(aSrc[0] + 192, ldsA[0]); GLDS(aSrc[1] + 192, ldsA[1]);
  GLDS(bSrc[0] + 192, ldsB[0]); GLDS(bSrc[1] + 192, ldsB[1]);
  __syncthreads();
  compute();

#pragma unroll
  for (int i = 0; i < 2; ++i)
#pragma unroll
    for (int j = 0; j < 2; ++j) {
      int col = j0 + wn + j * 16 + r16;  // global col in [0,256)
#pragma unroll
      for (int q = 0; q < 4; ++q) {
        int row = m0 + wm + i * 16 + g * 4 + q;
        if (row < NN) {
          if (col < 128) {
            P8[(size_t)row * 128 + col] = f2e4m3(acc[i][j][q]);
          } else {
            out[(size_t)row * 128 + (col - 128)] = acc[i][j][q] + b2[col - 128];
          }
        }
      }
    }
}

// ---------------- launch ----------------
extern "C" void kernel_launch(void* const* d_in, const int* in_sizes, int n_in,
                              void* d_out, int out_size, void* d_ws, size_t ws_size,
                              hipStream_t stream) {
  const float* x   = (const float*)d_in[0];
  const int*   ei  = (const int*)d_in[1];
  const float* Wl1 = (const float*)d_in[2];
  const float* Wr1 = (const float*)d_in[3];
  const float* b1  = (const float*)d_in[4];
  const float* Wl2 = (const float*)d_in[5];
  const float* Wr2 = (const float*)d_in[6];
  const float* b2  = (const float*)d_in[7];
  float* out = (float*)d_out;

  const int* src = ei;
  const int* dst = ei + NE;

  // workspace layout — NO OVERLAPS, peak ~68 MB:
  char* ws = (char*)d_ws;
  unsigned*       rowptr = (unsigned*)ws;                      // 0x0       + 200,004
  float*          inv    = (float*)(ws + 0x40000);             // 0x40000   + 200,000
  unsigned*       hist   = (unsigned*)(ws + 0x80000);          // 0x80000   + 256
  unsigned*       bases  = (unsigned*)(ws + 0x80400);          // 0x80400   + 260
  unsigned*       gcur   = (unsigned*)(ws + 0x80800);          // 0x80800   + 256
  unsigned short* esrc   = (unsigned short*)(ws + 0xC0000);    // 0xC0000   + 1.6MB
  unsigned*       bufA   = (unsigned*)(ws + 0x280000);         // 0x280000  + 3.2MB
  unsigned short* W1t    = (unsigned short*)(ws + 0x600000);   // 0x600000  + 0x20000
  unsigned short* W2t    = (unsigned short*)(ws + 0x620000);   // 0x620000  + 0x20000
  unsigned short* xb     = (unsigned short*)(ws + 0x700000);   // 0x700000  + 0xC35000
  unsigned short* meanb  = (unsigned short*)(ws + 0x1400000);  // 0x1400000 + 0xC35000
  unsigned short* h      = (unsigned short*)(ws + 0x2100000);  // 0x2100000 + 0x186A000
  unsigned char*  P8     = (unsigned char*)(ws + 0x3A00000);   // 0x3A00000 + 6.4MB

  const int TPB = 256;

  // prep (fused cvtx + mkw + hist zero) — no graph memset nodes
  prep_k<<<CVTB + 513, TPB, 0, stream>>>((const float4*)x, (uint2*)xb,
                                         Wl1, Wr1, Wl2, Wr2, W1t, W2t, hist);

  // CSR build: multi-split counting sort
  histC_k<<<MSB, TPB, 0, stream>>>(dst, hist);
  scan64_k<<<1, 64, 0, stream>>>(hist, bases, gcur);
  msplit_k<<<MSB, TPB, 0, stream>>>(src, dst, gcur, bufA);
  passB2_k<<<NBC, 1024, 0, stream>>>(bases, bufA, esrc, rowptr, inv);

  // layer 1
  gather_mean_k<<<(NN + 3) / 4, TPB, 0, stream>>>(esrc, rowptr, inv, (const unsigned*)xb, (unsigned*)meanb);
  mgemm1_k<<<3128, TPB, 0, stream>>>(xb, meanb, W1t, b1, h);

  // layer 2
  mgemm2_k<<<3128, TPB, 0, stream>>>(h, W2t, b2, P8, out);
  gather_add_k<<<(NN + 3) / 4, TPB, 0, stream>>>(esrc, rowptr, inv, (const unsigned short*)P8, out);
}

// Round 24
// 166.161 us; speedup vs baseline: 1.1538x; 1.0194x over previous
//
#include <hip/hip_runtime.h>

#define NN 50000
#define NE 800000
#define NBC 49            // coarse buckets of 1024 dst nodes
#define MSB 391           // msplit/hist-partial blocks (x2048 edges)

typedef __attribute__((ext_vector_type(8))) short short8;
typedef __attribute__((ext_vector_type(4))) float f32x4;

// global -> LDS direct DMA, 16B/lane, offset ALWAYS 0 (non-zero offset
// immediate is broken for this builtin — proven by round-13/14 bisection)
#define GLDS(g, l)                                                              \
  __builtin_amdgcn_global_load_lds(                                             \
      (const __attribute__((address_space(1))) void*)(g),                       \
      (__attribute__((address_space(3))) void*)(l), 16, 0, 0)

// ---------------- bf16 helpers (RNE) ----------------
__device__ __forceinline__ unsigned short f2bf(float f) {
  union { float f; unsigned u; } v; v.f = f;
  unsigned r = (v.u + 0x7FFFu + ((v.u >> 16) & 1u)) >> 16;
  return (unsigned short)r;
}
__device__ __forceinline__ float bflo(unsigned u) {
  union { unsigned x; float f; } v; v.x = u << 16; return v.f;
}
__device__ __forceinline__ float bfhi(unsigned u) {
  union { unsigned x; float f; } v; v.x = u & 0xFFFF0000u; return v.f;
}

// ---------------- fp8 e4m3 encode (RNE, subnormal-correct; r23-proven) ----------------
__device__ __forceinline__ unsigned char f2e4m3(float f) {
  unsigned u; __builtin_memcpy(&u, &f, 4);
  unsigned s = (u >> 24) & 0x80u;
  float av = fabsf(f);
  if (av < 0.015625f) {                       // subnormal: round(av*512) in 0..8
    int sub = (int)rintf(av * 512.0f);        // ==8 -> code 8 == min normal 2^-6
    return (unsigned char)(s | (unsigned)sub);
  }
  unsigned m = u & 0x7FFFFFFFu;
  unsigned r = (m + 0x7FFFFu + ((m >> 20) & 1u)) >> 20;  // RNE at bit20
  int e8 = (int)(r >> 3) - 120;               // re-bias 127->7
  if (e8 > 15) return (unsigned char)(s | 0x7Eu);
  return (unsigned char)(s | ((unsigned)e8 << 3) | (r & 7u));
}

// ---------------- threefry2x32, JAX partitionable, key = (0, 42) ----------------
__device__ __forceinline__ unsigned tf_rotl(unsigned x, int r) {
#if __has_builtin(__builtin_amdgcn_alignbit)
  return __builtin_amdgcn_alignbit(x, x, 32 - r);
#else
  return (x << r) | (x >> (32 - r));
#endif
}
__device__ __forceinline__ void threefry_0_42(unsigned x0, unsigned x1,
                                              unsigned& o0, unsigned& o1) {
  const unsigned k0 = 0u, k1 = 42u;
  const unsigned k2 = k0 ^ k1 ^ 0x1BD11BDAu;
  x0 += k0; x1 += k1;
#define TF_R(r) { x0 += x1; x1 = tf_rotl(x1, (r)); x1 ^= x0; }
  TF_R(13) TF_R(15) TF_R(26) TF_R(6)
  x0 += k1; x1 += k2 + 1u;
  TF_R(17) TF_R(29) TF_R(16) TF_R(24)
  x0 += k2; x1 += k0 + 2u;
  TF_R(13) TF_R(15) TF_R(26) TF_R(6)
  x0 += k0; x1 += k1 + 3u;
  TF_R(17) TF_R(29) TF_R(16) TF_R(24)
  x0 += k1; x1 += k2 + 4u;
  TF_R(13) TF_R(15) TF_R(26) TF_R(6)
  x0 += k2; x1 += k0 + 5u;
#undef TF_R
  o0 = x0; o1 = x1;
}
// keep iff uniform<0.9f; 0.9f == 7549747/2^23 exactly -> integer compare
__device__ __forceinline__ float dropout_scale(unsigned flat) {
  unsigned o0, o1;
  threefry_0_42(0u, flat, o0, o1);
  unsigned bits = o0 ^ o1;
  return ((bits >> 9) < 7549747u) ? (1.0f / 0.9f) : 0.0f;
}

// ---------------- fused prep: x->bf16 + weight packing + hist partials ----------------
// Hist blocks write per-block 64-bucket histograms to hpart[MSB][64]
// (full overwrite -> no zero init, no global atomics, no separate launch).
#define CVTB 6250  // 1.6M float4 / 256
__global__ void prep_k(const float4* __restrict__ x, uint2* __restrict__ xb,
                       const float* __restrict__ Wl1, const float* __restrict__ Wr1,
                       const float* __restrict__ Wl2, const float* __restrict__ Wr2,
                       unsigned short* __restrict__ W1t, unsigned short* __restrict__ W2t,
                       const int* __restrict__ dst, unsigned* __restrict__ hpart) {
  int bid = blockIdx.x;
  if (bid < CVTB) {
    int i = bid * 256 + threadIdx.x;
    float4 v = x[i];
    uint2 o;
    o.x = (unsigned)f2bf(v.x) | ((unsigned)f2bf(v.y) << 16);
    o.y = (unsigned)f2bf(v.z) | ((unsigned)f2bf(v.w) << 16);
    xb[i] = o;
  } else if (bid < CVTB + 512) {
    int gid = (bid - CVTB) * 256 + threadIdx.x;  // 131072
    int idx = gid & 65535;
    int n = idx >> 8, k = idx & 255;
    if (gid < 65536) {
      float v = (k < 128) ? Wr1[(size_t)k * 256 + n] : Wl1[(size_t)(k - 128) * 256 + n];
      W1t[idx] = f2bf(v);
    } else {
      float v = (n < 128) ? Wl2[(size_t)k * 128 + n] : Wr2[(size_t)k * 128 + (n - 128)];
      W2t[idx] = f2bf(v);
    }
  } else {
    __shared__ unsigned lh[64];
    int hb = bid - CVTB - 512;  // 0..MSB-1
    int tid = threadIdx.x;
    if (tid < 64) lh[tid] = 0;
    __syncthreads();
    int base = hb * 2048;
#pragma unroll
    for (int k = 0; k < 8; ++k) {
      int e = base + k * 256 + tid;
      if (e < NE) atomicAdd(&lh[((unsigned)dst[e]) >> 10], 1u);
    }
    __syncthreads();
    if (tid < 64) hpart[hb * 64 + tid] = lh[tid];
  }
}

// sum hist partials (4 summers/bucket) + exclusive wave-scan -> bases, gcur
__global__ __launch_bounds__(256) void scan256_k(const unsigned* __restrict__ hpart,
                                                 unsigned* __restrict__ bases,
                                                 unsigned* __restrict__ gcur) {
  __shared__ unsigned red[256];
  int t = threadIdx.x;
  int b = t & 63, p4 = t >> 6;  // 4 partial-summers per bucket
  unsigned s = 0;
#pragma unroll 4
  for (int p = p4; p < MSB; p += 4) s += hpart[p * 64 + b];
  red[t] = s;
  __syncthreads();
  if (t < 64) {
    unsigned v = red[t] + red[t + 64] + red[t + 128] + red[t + 192];
    unsigned incl = v;
#pragma unroll
    for (int o = 1; o < 64; o <<= 1) {
      unsigned tt = __shfl_up(incl, o);
      if (t >= o) incl += tt;
    }
    unsigned ex = incl - v;
    bases[t] = ex;
    gcur[t] = ex;
    if (t == 63) bases[64] = incl;  // = NE
  }
}

__global__ __launch_bounds__(256) void msplit_k(const int* __restrict__ src,
                                                const int* __restrict__ dst,
                                                unsigned* __restrict__ gcur,
                                                unsigned* __restrict__ bufA) {
  __shared__ unsigned lh[64], gb[64], lc[64];
  int tid = threadIdx.x;
  if (tid < 64) { lh[tid] = 0; lc[tid] = 0; }
  __syncthreads();
  int base = blockIdx.x * 2048;
  unsigned s[8], d[8];
  bool val[8];
#pragma unroll
  for (int k = 0; k < 8; ++k) {
    int e = base + k * 256 + tid;
    val[k] = (e < NE);
    s[k] = val[k] ? (unsigned)src[e] : 0u;
    d[k] = val[k] ? (unsigned)dst[e] : 0u;
    if (val[k]) atomicAdd(&lh[d[k] >> 10], 1u);
  }
  __syncthreads();
  if (tid < 64 && lh[tid]) gb[tid] = atomicAdd(&gcur[tid], lh[tid]);
  __syncthreads();
#pragma unroll
  for (int k = 0; k < 8; ++k) {
    if (val[k]) {
      unsigned b = d[k] >> 10;
      unsigned pos = atomicAdd(&lc[b], 1u);
      bufA[gb[b] + pos] = (s[k] & 0xFFFFu) | ((d[k] & 1023u) << 16);
    }
  }
}

__global__ __launch_bounds__(1024) void passB2_k(const unsigned* __restrict__ bases,
                                                 const unsigned* __restrict__ bufA,
                                                 unsigned short* __restrict__ esrc,
                                                 unsigned* __restrict__ rowptr,
                                                 float* __restrict__ inv) {
  __shared__ unsigned cnt[1024], offs[1024], s_[1024];
  __shared__ unsigned short stage[18432];
  const int b = blockIdx.x, tid = threadIdx.x;
  const unsigned base0 = bases[b];
  const unsigned end0 = bases[b + 1];
  const unsigned bcnt = end0 - base0;

  cnt[tid] = 0;
  __syncthreads();
  for (unsigned i = tid; i < bcnt; i += 1024)
    atomicAdd(&cnt[bufA[base0 + i] >> 16], 1u);
  __syncthreads();

  unsigned c = cnt[tid];
  s_[tid] = c;
  __syncthreads();
  for (int o = 1; o < 1024; o <<= 1) {
    unsigned t = (tid >= o) ? s_[tid - o] : 0u;
    __syncthreads();
    s_[tid] += t;
    __syncthreads();
  }
  unsigned ex = s_[tid] - c;
  offs[tid] = ex;
  int node = b * 1024 + tid;
  if (node < NN) {
    rowptr[node] = base0 + ex;
    inv[node] = 1.0f / fmaxf((float)c, 1.0f);
  }
  cnt[tid] = 0;  // -> cursor
  if (b == NBC - 1 && tid == 0) rowptr[NN] = NE;
  __syncthreads();

  if (bcnt <= 18432) {
    for (unsigned i = tid; i < bcnt; i += 1024) {
      unsigned w = bufA[base0 + i];
      unsigned dl = w >> 16;
      unsigned pos = atomicAdd(&cnt[dl], 1u);
      stage[offs[dl] + pos] = (unsigned short)w;
    }
    __syncthreads();
    for (unsigned i = tid; i < bcnt; i += 1024) esrc[base0 + i] = stage[i];
  } else {
    for (unsigned i = tid; i < bcnt; i += 1024) {
      unsigned w = bufA[base0 + i];
      unsigned dl = w >> 16;
      unsigned pos = atomicAdd(&cnt[dl], 1u);
      esrc[base0 + offs[dl] + pos] = (unsigned short)w;
    }
  }
}

// ---------------- gathers: wave-per-node full row, 8-deep MLP (r19-proven) ----------------
__global__ __launch_bounds__(256) void gather_mean_k(
    const unsigned short* __restrict__ esrc, const unsigned* __restrict__ rowptr,
    const float* __restrict__ inv, const unsigned* __restrict__ xb,
    unsigned* __restrict__ meanb) {
  int node = blockIdx.x * 4 + (threadIdx.x >> 6);
  if (node >= NN) return;
  int lane = threadIdx.x & 63;
  unsigned beg = rowptr[node], end = rowptr[node + 1];
  float ax = 0.f, ay = 0.f;
  unsigned t = beg;
  for (; t + 8 <= end; t += 8) {
    unsigned v0 = xb[(size_t)esrc[t + 0] * 64 + lane];
    unsigned v1 = xb[(size_t)esrc[t + 1] * 64 + lane];
    unsigned v2 = xb[(size_t)esrc[t + 2] * 64 + lane];
    unsigned v3 = xb[(size_t)esrc[t + 3] * 64 + lane];
    unsigned v4 = xb[(size_t)esrc[t + 4] * 64 + lane];
    unsigned v5 = xb[(size_t)esrc[t + 5] * 64 + lane];
    unsigned v6 = xb[(size_t)esrc[t + 6] * 64 + lane];
    unsigned v7 = xb[(size_t)esrc[t + 7] * 64 + lane];
    ax += ((bflo(v0) + bflo(v1)) + (bflo(v2) + bflo(v3))) +
          ((bflo(v4) + bflo(v5)) + (bflo(v6) + bflo(v7)));
    ay += ((bfhi(v0) + bfhi(v1)) + (bfhi(v2) + bfhi(v3))) +
          ((bfhi(v4) + bfhi(v5)) + (bfhi(v6) + bfhi(v7)));
  }
  for (; t + 4 <= end; t += 4) {
    unsigned v0 = xb[(size_t)esrc[t + 0] * 64 + lane];
    unsigned v1 = xb[(size_t)esrc[t + 1] * 64 + lane];
    unsigned v2 = xb[(size_t)esrc[t + 2] * 64 + lane];
    unsigned v3 = xb[(size_t)esrc[t + 3] * 64 + lane];
    ax += (bflo(v0) + bflo(v1)) + (bflo(v2) + bflo(v3));
    ay += (bfhi(v0) + bfhi(v1)) + (bfhi(v2) + bfhi(v3));
  }
  for (; t < end; ++t) {
    unsigned v0 = xb[(size_t)esrc[t] * 64 + lane];
    ax += bflo(v0); ay += bfhi(v0);
  }
  float sc = inv[node];
  meanb[(size_t)node * 64 + lane] =
      (unsigned)f2bf(ax * sc) | ((unsigned)f2bf(ay * sc) << 16);
}

// gather_add over fp8(e4m3) P: lane reads u16 = 2 fp8; decode via LDS table
__global__ __launch_bounds__(256) void gather_add_k(
    const unsigned short* __restrict__ esrc, const unsigned* __restrict__ rowptr,
    const float* __restrict__ inv, const unsigned short* __restrict__ P8,
    float* __restrict__ out) {
  __shared__ float tab[256];
  {
    int i = threadIdx.x;
    unsigned em = i & 0x7F;
    float v;
    if (em < 8) {
      v = (float)em * 0.001953125f;  // subnormal: em * 2^-9
    } else {
      unsigned bits = (((em >> 3) + 120u) << 23) | ((em & 7u) << 20);
      __builtin_memcpy(&v, &bits, 4);
    }
    tab[i] = (i & 0x80) ? -v : v;
  }
  __syncthreads();

  int node = blockIdx.x * 4 + (threadIdx.x >> 6);
  if (node >= NN) return;
  int lane = threadIdx.x & 63;
  unsigned beg = rowptr[node], end = rowptr[node + 1];
  float ax = 0.f, ay = 0.f;
  unsigned t = beg;
  for (; t + 8 <= end; t += 8) {
    unsigned w0 = P8[(size_t)esrc[t + 0] * 64 + lane];
    unsigned w1 = P8[(size_t)esrc[t + 1] * 64 + lane];
    unsigned w2 = P8[(size_t)esrc[t + 2] * 64 + lane];
    unsigned w3 = P8[(size_t)esrc[t + 3] * 64 + lane];
    unsigned w4 = P8[(size_t)esrc[t + 4] * 64 + lane];
    unsigned w5 = P8[(size_t)esrc[t + 5] * 64 + lane];
    unsigned w6 = P8[(size_t)esrc[t + 6] * 64 + lane];
    unsigned w7 = P8[(size_t)esrc[t + 7] * 64 + lane];
    ax += ((tab[w0 & 0xFFu] + tab[w1 & 0xFFu]) + (tab[w2 & 0xFFu] + tab[w3 & 0xFFu])) +
          ((tab[w4 & 0xFFu] + tab[w5 & 0xFFu]) + (tab[w6 & 0xFFu] + tab[w7 & 0xFFu]));
    ay += ((tab[w0 >> 8] + tab[w1 >> 8]) + (tab[w2 >> 8] + tab[w3 >> 8])) +
          ((tab[w4 >> 8] + tab[w5 >> 8]) + (tab[w6 >> 8] + tab[w7 >> 8]));
  }
  for (; t + 4 <= end; t += 4) {
    unsigned w0 = P8[(size_t)esrc[t + 0] * 64 + lane];
    unsigned w1 = P8[(size_t)esrc[t + 1] * 64 + lane];
    unsigned w2 = P8[(size_t)esrc[t + 2] * 64 + lane];
    unsigned w3 = P8[(size_t)esrc[t + 3] * 64 + lane];
    ax += (tab[w0 & 0xFFu] + tab[w1 & 0xFFu]) + (tab[w2 & 0xFFu] + tab[w3 & 0xFFu]);
    ay += (tab[w0 >> 8] + tab[w1 >> 8]) + (tab[w2 >> 8] + tab[w3 >> 8]);
  }
  for (; t < end; ++t) {
    unsigned w0 = P8[(size_t)esrc[t] * 64 + lane];
    ax += tab[w0 & 0xFFu];
    ay += tab[w0 >> 8];
  }
  float sc = inv[node];
  float2* O = (float2*)out;
  float2 o = O[(size_t)node * 64 + lane];
  o.x += ax * sc;
  o.y += ay * sc;
  O[(size_t)node * 64 + lane] = o;
}

// ---------------- MFMA GEMMs: 64x64 tile, single-buffer LDS (r14/r19-proven) ----------------
// min-waves hint requests full 8-block/CU co-residency (VGPR 44 < 64 budget).
__global__ __launch_bounds__(256, 8) void mgemm1_k(
    const unsigned short* __restrict__ xb, const unsigned short* __restrict__ meanb,
    const unsigned short* __restrict__ W1t, const float* __restrict__ b1,
    unsigned short* __restrict__ h) {
  __shared__ __align__(16) char As[64 * 64 * 2];
  __shared__ __align__(16) char Bs[64 * 64 * 2];
  const int tid = threadIdx.x;
  const int lane = tid & 63, wid = tid >> 6;
  const int wm = (wid >> 1) * 32, wn = (wid & 1) * 32;
  const int r16 = lane & 15, g = lane >> 4;
  const unsigned bid = blockIdx.x;
  const unsigned v_ = (bid & 7u) * 391u + (bid >> 3);  // bijective: 3128 = 8*391
  const int m0 = (int)(v_ >> 2) * 64;
  const int j0 = (int)(v_ & 3u) * 64;
  const int wbase = (tid & ~63);

  const unsigned short* aSrcX[2];
  const unsigned short* aSrcM[2];
  const unsigned short* bSrc[2];
  char* ldsA[2];
  char* ldsB[2];
#pragma unroll
  for (int p = 0; p < 2; ++p) {
    int id = p * 256 + tid;
    int r = id >> 3, cb = id & 7;
    int grow = m0 + r;
    if (grow >= NN) grow = NN - 1;            // dead rows, masked at store
    int swz = (cb ^ (r & 7)) << 3;            // element offset of 16B chunk
    aSrcX[p] = xb + (size_t)grow * 128 + swz;
    aSrcM[p] = meanb + (size_t)grow * 128 + swz;
    bSrc[p] = W1t + (size_t)(j0 + r) * 256 + swz;
    ldsA[p] = As + ((p * 256 + wbase) << 4);
    ldsB[p] = Bs + ((p * 256 + wbase) << 4);
  }

  int aoff[2][2], boff[2][2];
#pragma unroll
  for (int f = 0; f < 2; ++f)
#pragma unroll
    for (int ks = 0; ks < 2; ++ks) {
      int ar = wm + f * 16 + r16;
      aoff[f][ks] = ar * 128 + ((ks * 64 + g * 16) ^ ((ar & 7) << 4));
      int br = wn + f * 16 + r16;
      boff[f][ks] = br * 128 + ((ks * 64 + g * 16) ^ ((br & 7) << 4));
    }

  f32x4 acc[2][2] = {};

  auto compute = [&]() {
#pragma unroll
    for (int ks = 0; ks < 2; ++ks) {
      short8 af[2], bf[2];
#pragma unroll
      for (int f = 0; f < 2; ++f) {
        af[f] = *(const short8*)(As + aoff[f][ks]);
        bf[f] = *(const short8*)(Bs + boff[f][ks]);
      }
#pragma unroll
      for (int i = 0; i < 2; ++i)
#pragma unroll
        for (int j = 0; j < 2; ++j)
          acc[i][j] = __builtin_amdgcn_mfma_f32_16x16x32_bf16(af[i], bf[j], acc[i][j], 0, 0, 0);
    }
  };

  // s=0: A from xb k0=0
  GLDS(aSrcX[0], ldsA[0]); GLDS(aSrcX[1], ldsA[1]);
  GLDS(bSrc[0], ldsB[0]);  GLDS(bSrc[1], ldsB[1]);

  // dropout scales overlap stage-0 flight (proven placement)
  float dsc[2][2][4];
#pragma unroll
  for (int i = 0; i < 2; ++i)
#pragma unroll
    for (int j = 0; j < 2; ++j) {
      int col = j0 + wn + j * 16 + r16;
#pragma unroll
      for (int q = 0; q < 4; ++q) {
        int row = m0 + wm + i * 16 + g * 4 + q;
        dsc[i][j][q] = dropout_scale((unsigned)row * 256u + (unsigned)col);
      }
    }

  __syncthreads();
  compute();
  __syncthreads();
  // s=1: A from xb k0=64
  GLDS(aSrcX[0] + 64, ldsA[0]); GLDS(aSrcX[1] + 64, ldsA[1]);
  GLDS(bSrc[0] + 64, ldsB[0]);  GLDS(bSrc[1] + 64, ldsB[1]);
  __syncthreads();
  compute();
  __syncthreads();
  // s=2: A from meanb k0=0
  GLDS(aSrcM[0], ldsA[0]);       GLDS(aSrcM[1], ldsA[1]);
  GLDS(bSrc[0] + 128, ldsB[0]);  GLDS(bSrc[1] + 128, ldsB[1]);
  __syncthreads();
  compute();
  __syncthreads();
  // s=3: A from meanb k0=64
  GLDS(aSrcM[0] + 64, ldsA[0]);  GLDS(aSrcM[1] + 64, ldsA[1]);
  GLDS(bSrc[0] + 192, ldsB[0]);  GLDS(bSrc[1] + 192, ldsB[1]);
  __syncthreads();
  compute();

#pragma unroll
  for (int i = 0; i < 2; ++i)
#pragma unroll
    for (int j = 0; j < 2; ++j) {
      int col = j0 + wn + j * 16 + r16;
      float bias = b1[col];
#pragma unroll
      for (int q = 0; q < 4; ++q) {
        int row = m0 + wm + i * 16 + g * 4 + q;
        if (row < NN) {
          float v = fmaxf(acc[i][j][q] + bias, 0.f) * dsc[i][j][q];
          h[(size_t)row * 256 + col] = f2bf(v);
        }
      }
    }
}

__global__ __launch_bounds__(256, 8) void mgemm2_k(
    const unsigned short* __restrict__ h, const unsigned short* __restrict__ W2t,
    const float* __restrict__ b2, unsigned char* __restrict__ P8,
    float* __restrict__ out) {
  __shared__ __align__(16) char As[64 * 64 * 2];
  __shared__ __align__(16) char Bs[64 * 64 * 2];
  const int tid = threadIdx.x;
  const int lane = tid & 63, wid = tid >> 6;
  const int wm = (wid >> 1) * 32, wn = (wid & 1) * 32;
  const int r16 = lane & 15, g = lane >> 4;
  const unsigned bid = blockIdx.x;
  const unsigned v_ = (bid & 7u) * 391u + (bid >> 3);
  const int m0 = (int)(v_ >> 2) * 64;
  const int j0 = (int)(v_ & 3u) * 64;
  const int wbase = (tid & ~63);

  const unsigned short* aSrc[2];
  const unsigned short* bSrc[2];
  char* ldsA[2];
  char* ldsB[2];
#pragma unroll
  for (int p = 0; p < 2; ++p) {
    int id = p * 256 + tid;
    int r = id >> 3, cb = id & 7;
    int grow = m0 + r;
    if (grow >= NN) grow = NN - 1;
    int swz = (cb ^ (r & 7)) << 3;
    aSrc[p] = h + (size_t)grow * 256 + swz;
    bSrc[p] = W2t + (size_t)(j0 + r) * 256 + swz;
    ldsA[p] = As + ((p * 256 + wbase) << 4);
    ldsB[p] = Bs + ((p * 256 + wbase) << 4);
  }

  int aoff[2][2], boff[2][2];
#pragma unroll
  for (int f = 0; f < 2; ++f)
#pragma unroll
    for (int ks = 0; ks < 2; ++ks) {
      int ar = wm + f * 16 + r16;
      aoff[f][ks] = ar * 128 + ((ks * 64 + g * 16) ^ ((ar & 7) << 4));
      int br = wn + f * 16 + r16;
      boff[f][ks] = br * 128 + ((ks * 64 + g * 16) ^ ((br & 7) << 4));
    }

  f32x4 acc[2][2] = {};

  auto compute = [&]() {
#pragma unroll
    for (int ks = 0; ks < 2; ++ks) {
      short8 af[2], bf[2];
#pragma unroll
      for (int f = 0; f < 2; ++f) {
        af[f] = *(const short8*)(As + aoff[f][ks]);
        bf[f] = *(const short8*)(Bs + boff[f][ks]);
      }
#pragma unroll
      for (int i = 0; i < 2; ++i)
#pragma unroll
        for (int j = 0; j < 2; ++j)
          acc[i][j] = __builtin_amdgcn_mfma_f32_16x16x32_bf16(af[i], bf[j], acc[i][j], 0, 0, 0);
    }
  };

  GLDS(aSrc[0], ldsA[0]); GLDS(aSrc[1], ldsA[1]);
  GLDS(bSrc[0], ldsB[0]); GLDS(bSrc[1], ldsB[1]);
  __syncthreads();
  compute();
  __syncthreads();
  GLDS(aSrc[0] + 64, ldsA[0]); GLDS(aSrc[1] + 64, ldsA[1]);
  GLDS(bSrc[0] + 64, ldsB[0]); GLDS(bSrc[1] + 64, ldsB[1]);
  __syncthreads();
  compute();
  __syncthreads();
  GLDS(aSrc[0] + 128, ldsA[0]); GLDS(aSrc[1] + 128, ldsA[1]);
  GLDS(bSrc[0] + 128, ldsB[0]); GLDS(bSrc[1] + 128, ldsB[1]);
  __syncthreads();
  compute();
  __syncthreads();
  GLDS(aSrc[0] + 192, ldsA[0]); GLDS(aSrc[1] + 192, ldsA[1]);
  GLDS(bSrc[0] + 192, ldsB[0]); GLDS(bSrc[1] + 192, ldsB[1]);
  __syncthreads();
  compute();

#pragma unroll
  for (int i = 0; i < 2; ++i)
#pragma unroll
    for (int j = 0; j < 2; ++j) {
      int col = j0 + wn + j * 16 + r16;  // global col in [0,256)
#pragma unroll
      for (int q = 0; q < 4; ++q) {
        int row = m0 + wm + i * 16 + g * 4 + q;
        if (row < NN) {
          if (col < 128) {
            P8[(size_t)row * 128 + col] = f2e4m3(acc[i][j][q]);
          } else {
            out[(size_t)row * 128 + (col - 128)] = acc[i][j][q] + b2[col - 128];
          }
        }
      }
    }
}

// ---------------- launch ----------------
extern "C" void kernel_launch(void* const* d_in, const int* in_sizes, int n_in,
                              void* d_out, int out_size, void* d_ws, size_t ws_size,
                              hipStream_t stream) {
  const float* x   = (const float*)d_in[0];
  const int*   ei  = (const int*)d_in[1];
  const float* Wl1 = (const float*)d_in[2];
  const float* Wr1 = (const float*)d_in[3];
  const float* b1  = (const float*)d_in[4];
  const float* Wl2 = (const float*)d_in[5];
  const float* Wr2 = (const float*)d_in[6];
  const float* b2  = (const float*)d_in[7];
  float* out = (float*)d_out;

  const int* src = ei;
  const int* dst = ei + NE;

  // workspace layout — NO OVERLAPS, peak ~68 MB:
  char* ws = (char*)d_ws;
  unsigned*       rowptr = (unsigned*)ws;                      // 0x0       + 200,004
  float*          inv    = (float*)(ws + 0x40000);             // 0x40000   + 200,000
  unsigned*       hpart  = (unsigned*)(ws + 0x80000);          // 0x80000   + 100,096
  unsigned*       bases  = (unsigned*)(ws + 0xA0000);          // 0xA0000   + 260
  unsigned*       gcur   = (unsigned*)(ws + 0xA0400);          // 0xA0400   + 256
  unsigned short* esrc   = (unsigned short*)(ws + 0xC0000);    // 0xC0000   + 1.6MB
  unsigned*       bufA   = (unsigned*)(ws + 0x280000);         // 0x280000  + 3.2MB
  unsigned short* W1t    = (unsigned short*)(ws + 0x600000);   // 0x600000  + 0x20000
  unsigned short* W2t    = (unsigned short*)(ws + 0x620000);   // 0x620000  + 0x20000
  unsigned short* xb     = (unsigned short*)(ws + 0x700000);   // 0x700000  + 0xC35000
  unsigned short* meanb  = (unsigned short*)(ws + 0x1400000);  // 0x1400000 + 0xC35000
  unsigned short* h      = (unsigned short*)(ws + 0x2100000);  // 0x2100000 + 0x186A000
  unsigned char*  P8     = (unsigned char*)(ws + 0x3A00000);   // 0x3A00000 + 6.4MB

  const int TPB = 256;

  // prep: cvt + weights + hist partials (histC fused in; no zero/no memset)
  prep_k<<<CVTB + 512 + MSB, TPB, 0, stream>>>((const float4*)x, (uint2*)xb,
                                               Wl1, Wr1, Wl2, Wr2, W1t, W2t,
                                               dst, hpart);

  // CSR build: multi-split counting sort
  scan256_k<<<1, TPB, 0, stream>>>(hpart, bases, gcur);
  msplit_k<<<MSB, TPB, 0, stream>>>(src, dst, gcur, bufA);
  passB2_k<<<NBC, 1024, 0, stream>>>(bases, bufA, esrc, rowptr, inv);

  // layer 1
  gather_mean_k<<<(NN + 3) / 4, TPB, 0, stream>>>(esrc, rowptr, inv, (const unsigned*)xb, (unsigned*)meanb);
  mgemm1_k<<<3128, TPB, 0, stream>>>(xb, meanb, W1t, b1, h);

  // layer 2
  mgemm2_k<<<3128, TPB, 0, stream>>>(h, W2t, b2, P8, out);
  gather_add_k<<<(NN + 3) / 4, TPB, 0, stream>>>(esrc, rowptr, inv, (const unsigned short*)P8, out);
}